// Round 1
// baseline (112.264 us; speedup 1.0000x reference)
//
#include <hip/hip_runtime.h>

#define HCH 32
#define NDIM 1024

using half8 = __attribute__((ext_vector_type(8))) _Float16;
using floatx16 = __attribute__((ext_vector_type(16))) float;

// One wave per (b,i) row. Per 32-pixel tile along j:
//   layer1 in VALU f32 (2 fma + relu per channel, 16 ch/lane),
//   layer2 as 2x v_mfma_f32_32x32x16_f16 computing D[c][pixel] = W2^T(f16) . h1^T(f16) + b2,
//   layer3 as per-lane 16-term dot with W3 + one shfl_xor(32),
//   softplus in f32, coalesced 128B store from lanes 0..31.
__global__ __launch_bounds__(256, 4)
void lf_kernel(const float* __restrict__ weights,
               const float* __restrict__ distances,
               const float* __restrict__ W1,
               const float* __restrict__ b1,
               const float* __restrict__ W2,
               const float* __restrict__ b2,
               const float* __restrict__ W3,
               const float* __restrict__ b3,
               float* __restrict__ out,
               int rows_total)
{
    const int lane = threadIdx.x & 63;
    const int row_id = blockIdx.x * 4 + (threadIdx.x >> 6);
    if (row_id >= rows_total) return;

    const int b = row_id >> 10;            // N = 1024
    const int i = row_id & (NDIM - 1);

    const int col = lane & 31;             // pixel-in-tile (B n-index, D col)
    const int half_id = lane >> 5;
    const int kb = half_id * 8;            // k-block base for A/B frags

    const float wi = weights[row_id];

    // Layer-1 constants for this lane's 16 channels: {kb..kb+7} and {16+kb..16+kb+7}.
    // base = W1[0,ch]*wi + b1[ch] folded once per row (wi is row-constant).
    float base0[8], c0[8], e0[8], base1[8], c1[8], e1[8];
#pragma unroll
    for (int j = 0; j < 8; ++j) {
        const int ch0 = kb + j;
        const int ch1 = 16 + kb + j;
        base0[j] = fmaf(W1[ch0], wi, b1[ch0]);
        c0[j]    = W1[HCH + ch0];
        e0[j]    = W1[2 * HCH + ch0];
        base1[j] = fmaf(W1[ch1], wi, b1[ch1]);
        c1[j]    = W1[HCH + ch1];
        e1[j]    = W1[2 * HCH + ch1];
    }

    // A fragments: A[m=c][k=h] = W2[h][c];  c = col, h = kb+j (frag0), 16+kb+j (frag1)
    half8 a0, a1;
#pragma unroll
    for (int j = 0; j < 8; ++j) {
        a0[j] = (_Float16)W2[(kb + j) * HCH + col];
        a1[j] = (_Float16)W2[(16 + kb + j) * HCH + col];
    }

    // C-init = b2 broadcast along cols; W3 gathered per accumulator register.
    // D row for reg r: (r&3) + 8*(r>>2) + 4*half_id  [measured C/D layout, 32x32]
    floatx16 cinit;
    float w3r[16];
#pragma unroll
    for (int r = 0; r < 16; ++r) {
        const int rc = (r & 3) + 8 * (r >> 2) + 4 * half_id;
        cinit[r] = b2[rc];
        w3r[r]   = W3[rc];
    }
    const float b3v = b3[0];

    const float* __restrict__ drow = distances + (size_t)(b * NDIM + i) * NDIM;
    const float* __restrict__ wrow = weights + b * NDIM;
    float* __restrict__ orow = out + (size_t)(b * NDIM + i) * NDIM;

    // Software prefetch of the streaming d / wj values.
    float d_cur  = drow[col];
    float wj_cur = wrow[col];

    for (int j0 = 0; j0 < NDIM; j0 += 32) {
        const int jn = (j0 + 32 < NDIM) ? (j0 + 32 + col) : col;
        const float d_nxt  = drow[jn];
        const float wj_nxt = wrow[jn];

        // Layer 1 (f32) -> f16 B fragments: B[k=ch][n=pixel=col]
        half8 bf0, bf1;
#pragma unroll
        for (int j = 0; j < 8; ++j) {
            const float h0 = fmaxf(fmaf(e0[j], d_cur, fmaf(c0[j], wj_cur, base0[j])), 0.0f);
            const float h1 = fmaxf(fmaf(e1[j], d_cur, fmaf(c1[j], wj_cur, base1[j])), 0.0f);
            bf0[j] = (_Float16)h0;
            bf1[j] = (_Float16)h1;
        }

        // Layer 2: D[c][pixel] = W2^T . h1 + b2   (K=32 via two K=16 MFMAs)
        floatx16 acc = __builtin_amdgcn_mfma_f32_32x32x16_f16(a0, bf0, cinit, 0, 0, 0);
        acc = __builtin_amdgcn_mfma_f32_32x32x16_f16(a1, bf1, acc, 0, 0, 0);

        // Layer 3: relu + dot with W3 over this lane's 16 channels, then
        // combine with the complementary 16 channels held by lane^32.
        float s0 = 0.0f, s1 = 0.0f, s2 = 0.0f, s3 = 0.0f;
#pragma unroll
        for (int r = 0; r < 16; r += 4) {
            s0 = fmaf(fmaxf(acc[r + 0], 0.0f), w3r[r + 0], s0);
            s1 = fmaf(fmaxf(acc[r + 1], 0.0f), w3r[r + 1], s1);
            s2 = fmaf(fmaxf(acc[r + 2], 0.0f), w3r[r + 2], s2);
            s3 = fmaf(fmaxf(acc[r + 3], 0.0f), w3r[r + 3], s3);
        }
        float s = (s0 + s1) + (s2 + s3);
        s += __shfl_xor(s, 32, 64);

        // softplus(x) = max(x,0) + log(1 + exp(-|x|))
        const float x = s + b3v;
        const float sp = fmaxf(x, 0.0f) + __logf(1.0f + __expf(-fabsf(x)));

        if (lane < 32) orow[j0 + col] = sp;

        d_cur = d_nxt;
        wj_cur = wj_nxt;
    }
}

extern "C" void kernel_launch(void* const* d_in, const int* in_sizes, int n_in,
                              void* d_out, int out_size, void* d_ws, size_t ws_size,
                              hipStream_t stream) {
    const float* weights   = (const float*)d_in[0];
    const float* distances = (const float*)d_in[1];
    const float* W1 = (const float*)d_in[2];
    const float* b1 = (const float*)d_in[3];
    const float* W2 = (const float*)d_in[4];
    const float* b2 = (const float*)d_in[5];
    const float* W3 = (const float*)d_in[6];
    const float* b3 = (const float*)d_in[7];
    float* out = (float*)d_out;

    const int rows_total = 4 * 1024;       // B * N
    dim3 grid(rows_total / 4);             // 4 waves (1 row each) per 256-thread block
    lf_kernel<<<grid, 256, 0, stream>>>(weights, distances, W1, b1, W2, b2, W3, b3,
                                        out, rows_total);
}

// Round 3
// 107.500 us; speedup vs baseline: 1.0443x; 1.0443x over previous
//
#include <hip/hip_runtime.h>

#define HCH 32
#define NDIM 1024
#define TILE 32
#define SEG 256                 // pixels per wave (quarter row)
#define SEG_ITERS (SEG / TILE)  // 8

using half2v   = __attribute__((ext_vector_type(2))) _Float16;
using half8    = __attribute__((ext_vector_type(8))) _Float16;
using floatx16 = __attribute__((ext_vector_type(16))) float;

// One wave per quarter-row (b,i,seg). Per 32-pixel tile:
//   layer1 in packed f16 (2x v_pk_fma_f16 + v_pk_max_f16 per channel pair),
//   layer2 as 2x v_mfma_f32_32x32x16_f16: D[c][pixel] = W2^T . h1 + b2,
//   layer3 as f32 relu+fma dot with W3 + one shfl_xor(32),
//   softplus f32, coalesced 128B store from lanes 0..31.
__global__ __launch_bounds__(256, 4)
void lf_kernel(const float* __restrict__ weights,
               const float* __restrict__ distances,
               const float* __restrict__ W1,
               const float* __restrict__ b1,
               const float* __restrict__ W2,
               const float* __restrict__ b2,
               const float* __restrict__ W3,
               const float* __restrict__ b3,
               float* __restrict__ out)
{
    const int lane = threadIdx.x & 63;
    const int wave_gid = blockIdx.x * 4 + (threadIdx.x >> 6);
    const int row_id = wave_gid >> 2;         // (b,i) row
    const int seg = wave_gid & 3;             // quarter within the row
    const int b = row_id >> 10;               // N = 1024
    const int j_begin = seg * SEG;

    const int col = lane & 31;                // pixel-in-tile (B n-index, D col)
    const int half_id = lane >> 5;
    const int kb = half_id * 8;               // k-block base for A/B frags

    const float wi = weights[row_id];

    // Layer-1 constants as f16 pairs. Pair p<4 -> channels kb+2p,kb+2p+1 (frag0);
    // p>=4 -> 16+kb+2(p-4)+{0,1} (frag1). base = W1[0,ch]*wi + b1[ch] (f32 fold).
    half2v base2[8], cc2[8], ee2[8];
#pragma unroll
    for (int p = 0; p < 8; ++p) {
        const int chA = (p < 4) ? (kb + 2 * p) : (16 + kb + 2 * (p - 4));
        const int chB = chA + 1;
        base2[p] = half2v{(_Float16)fmaf(W1[chA], wi, b1[chA]),
                          (_Float16)fmaf(W1[chB], wi, b1[chB])};
        cc2[p] = half2v{(_Float16)W1[HCH + chA], (_Float16)W1[HCH + chB]};
        ee2[p] = half2v{(_Float16)W1[2 * HCH + chA], (_Float16)W1[2 * HCH + chB]};
    }

    // A fragments: A[m=c][k=h] = W2[h][c]; c = col, h = kb+j / 16+kb+j.
    half8 a0, a1;
#pragma unroll
    for (int j = 0; j < 8; ++j) {
        a0[j] = (_Float16)W2[(kb + j) * HCH + col];
        a1[j] = (_Float16)W2[(16 + kb + j) * HCH + col];
    }

    // C-init = b2 broadcast along cols; W3 gathered per accumulator register.
    // D row for reg r: (r&3) + 8*(r>>2) + 4*half_id  [measured C/D layout, 32x32]
    floatx16 cinit;
    float w3r[16];
#pragma unroll
    for (int r = 0; r < 16; ++r) {
        const int rc = (r & 3) + 8 * (r >> 2) + 4 * half_id;
        cinit[r] = b2[rc];
        w3r[r]   = W3[rc];
    }
    const float b3v = b3[0];

    const float* __restrict__ drow = distances + (size_t)row_id * NDIM;
    const float* __restrict__ wrow = weights + b * NDIM;
    float* __restrict__ orow = out + (size_t)row_id * NDIM;

    // Hoist all segment loads: 16 loads in flight, latency paid once.
    float d_t[SEG_ITERS], wj_t[SEG_ITERS];
#pragma unroll
    for (int t = 0; t < SEG_ITERS; ++t) {
        d_t[t]  = drow[j_begin + t * TILE + col];
        wj_t[t] = wrow[j_begin + t * TILE + col];
    }

    const half2v zero2 = half2v{(_Float16)0.0f, (_Float16)0.0f};

#pragma unroll
    for (int t = 0; t < SEG_ITERS; ++t) {
        const int j0 = j_begin + t * TILE;

        // Layer 1 (packed f16): h = max(e*d + (c*wj + base), 0)
        const _Float16 dh  = (_Float16)d_t[t];
        const _Float16 wjh = (_Float16)wj_t[t];
        const half2v d2  = half2v{dh, dh};
        const half2v wj2 = half2v{wjh, wjh};

        union Frag { half8 v; half2v h[4]; } u0, u1;
#pragma unroll
        for (int p = 0; p < 4; ++p) {
            half2v t0 = __builtin_elementwise_fma(cc2[p], wj2, base2[p]);
            t0 = __builtin_elementwise_fma(ee2[p], d2, t0);
            u0.h[p] = __builtin_elementwise_max(t0, zero2);
            half2v t1 = __builtin_elementwise_fma(cc2[p + 4], wj2, base2[p + 4]);
            t1 = __builtin_elementwise_fma(ee2[p + 4], d2, t1);
            u1.h[p] = __builtin_elementwise_max(t1, zero2);
        }

        // Layer 2: D[c][pixel] = W2^T . h1 + b2   (K=32 via two K=16 MFMAs)
        floatx16 acc = __builtin_amdgcn_mfma_f32_32x32x16_f16(a0, u0.v, cinit, 0, 0, 0);
        acc = __builtin_amdgcn_mfma_f32_32x32x16_f16(a1, u1.v, acc, 0, 0, 0);

        // Layer 3: relu + dot with W3 over this lane's 16 channels, then
        // combine with the complementary 16 channels held by lane^32.
        float s0 = 0.0f, s1 = 0.0f, s2 = 0.0f, s3 = 0.0f;
#pragma unroll
        for (int r = 0; r < 16; r += 4) {
            s0 = fmaf(fmaxf(acc[r + 0], 0.0f), w3r[r + 0], s0);
            s1 = fmaf(fmaxf(acc[r + 1], 0.0f), w3r[r + 1], s1);
            s2 = fmaf(fmaxf(acc[r + 2], 0.0f), w3r[r + 2], s2);
            s3 = fmaf(fmaxf(acc[r + 3], 0.0f), w3r[r + 3], s3);
        }
        float s = (s0 + s1) + (s2 + s3);
        s += __shfl_xor(s, 32, 64);

        // softplus(x) = max(x,0) + log(1 + exp(-|x|))
        const float x = s + b3v;
        const float sp = fmaxf(x, 0.0f) + __logf(1.0f + __expf(-fabsf(x)));

        if (lane < 32) orow[j0 + col] = sp;
    }
}

extern "C" void kernel_launch(void* const* d_in, const int* in_sizes, int n_in,
                              void* d_out, int out_size, void* d_ws, size_t ws_size,
                              hipStream_t stream) {
    const float* weights   = (const float*)d_in[0];
    const float* distances = (const float*)d_in[1];
    const float* W1 = (const float*)d_in[2];
    const float* b1 = (const float*)d_in[3];
    const float* W2 = (const float*)d_in[4];
    const float* b2 = (const float*)d_in[5];
    const float* W3 = (const float*)d_in[6];
    const float* b3 = (const float*)d_in[7];
    float* out = (float*)d_out;

    const int rows_total = 4 * 1024;            // B * N
    dim3 grid(rows_total * (NDIM / SEG) / 4);   // 4 waves/block, 1 quarter-row each
    lf_kernel<<<grid, 256, 0, stream>>>(weights, distances, W1, b1, W2, b2, W3, b3, out);
}

// Round 4
// 102.104 us; speedup vs baseline: 1.0995x; 1.0528x over previous
//
#include <hip/hip_runtime.h>

#define HCH 32
#define NDIM 1024
#define SEG 512                  // pixels per wave (half row)
#define PAIRS (SEG / 64)         // 8 iterations of 64 px (2 MFMA tiles)

using half2v   = __attribute__((ext_vector_type(2))) _Float16;
using half8    = __attribute__((ext_vector_type(8))) _Float16;
using floatx16 = __attribute__((ext_vector_type(16))) float;

// One wave per half-row (b,i,seg). Per 64-pixel pair (two 32-px MFMA tiles,
// independent streams for ILP):
//   layer1 packed f16 -> 2x v_mfma_f32_32x32x16_f16 per tile (D[ch][px]),
//   f32 relu+fma dot with W3 per tile, ONE shfl_xor(32) resolves both tiles,
//   one softplus pass over 64 distinct pixels, one coalesced 256B store.
__global__ __launch_bounds__(256, 4)
void lf_kernel(const float* __restrict__ weights,
               const float* __restrict__ distances,
               const float* __restrict__ W1,
               const float* __restrict__ b1,
               const float* __restrict__ W2,
               const float* __restrict__ b2,
               const float* __restrict__ W3,
               const float* __restrict__ b3,
               float* __restrict__ out)
{
    const int lane = threadIdx.x & 63;
    const int wave_gid = blockIdx.x * 4 + (threadIdx.x >> 6);
    const int row_id = wave_gid >> 1;          // (b,i) row
    const int j_begin = (wave_gid & 1) * SEG;  // half within the row
    const int b = row_id >> 10;                // N = 1024

    const int col = lane & 31;                 // pixel-in-tile (B n-index, D col)
    const int half_id = lane >> 5;
    const bool hi = (half_id != 0);
    const int kb = half_id * 8;                // k-block base for A/B frags

    const float wi = weights[row_id];

    // Layer-1 constants as f16 pairs. Pair p<4 -> channels kb+2p,+1 (frag0);
    // p>=4 -> 16+kb+2(p-4)+{0,1} (frag1). base = W1[0,ch]*wi + b1[ch] (f32 fold).
    half2v base2[8], cc2[8], ee2[8];
#pragma unroll
    for (int p = 0; p < 8; ++p) {
        const int chA = (p < 4) ? (kb + 2 * p) : (16 + kb + 2 * (p - 4));
        const int chB = chA + 1;
        base2[p] = half2v{(_Float16)fmaf(W1[chA], wi, b1[chA]),
                          (_Float16)fmaf(W1[chB], wi, b1[chB])};
        cc2[p] = half2v{(_Float16)W1[HCH + chA], (_Float16)W1[HCH + chB]};
        ee2[p] = half2v{(_Float16)W1[2 * HCH + chA], (_Float16)W1[2 * HCH + chB]};
    }

    // A fragments: A[m=c][k=h] = W2[h][c]; c = col, h = kb+j / 16+kb+j.
    half8 a0, a1;
#pragma unroll
    for (int j = 0; j < 8; ++j) {
        a0[j] = (_Float16)W2[(kb + j) * HCH + col];
        a1[j] = (_Float16)W2[(16 + kb + j) * HCH + col];
    }

    // C-init = b2 broadcast along cols; W3 gathered per accumulator register.
    // D row for reg r: (r&3) + 8*(r>>2) + 4*half_id  [measured C/D layout, 32x32]
    floatx16 cinit;
    float w3r[16];
#pragma unroll
    for (int r = 0; r < 16; ++r) {
        const int rc = (r & 3) + 8 * (r >> 2) + 4 * half_id;
        cinit[r] = b2[rc];
        w3r[r]   = W3[rc];
    }
    const float b3v = b3[0];

    const float* __restrict__ drow = distances + (size_t)row_id * NDIM;
    const float* __restrict__ wrow = weights + b * NDIM;
    float* __restrict__ orow = out + (size_t)row_id * NDIM;

    const half2v zero2 = half2v{(_Float16)0.0f, (_Float16)0.0f};

    // Streaming values, prefetch distance 1 pair.
    float dA  = drow[j_begin + col];
    float wjA = wrow[j_begin + col];
    float dB  = drow[j_begin + 32 + col];
    float wjB = wrow[j_begin + 32 + col];

#pragma unroll
    for (int p = 0; p < PAIRS; ++p) {
        const int j0 = j_begin + p * 64;
        const int jn = (p + 1 < PAIRS) ? (j0 + 64) : j_begin;
        const float dA_n  = drow[jn + col];
        const float wjA_n = wrow[jn + col];
        const float dB_n  = drow[jn + 32 + col];
        const float wjB_n = wrow[jn + 32 + col];

        // ---- Layer 1 (packed f16), two independent tiles ----
        const _Float16 dhA = (_Float16)dA, wjhA = (_Float16)wjA;
        const _Float16 dhB = (_Float16)dB, wjhB = (_Float16)wjB;
        const half2v d2A = half2v{dhA, dhA}, wj2A = half2v{wjhA, wjhA};
        const half2v d2B = half2v{dhB, dhB}, wj2B = half2v{wjhB, wjhB};

        union Frag { half8 v; half2v h[4]; } a0A, a1A, a0B, a1B;
#pragma unroll
        for (int q = 0; q < 4; ++q) {
            half2v tA0 = __builtin_elementwise_fma(cc2[q], wj2A, base2[q]);
            tA0 = __builtin_elementwise_fma(ee2[q], d2A, tA0);
            a0A.h[q] = __builtin_elementwise_max(tA0, zero2);
            half2v tA1 = __builtin_elementwise_fma(cc2[q + 4], wj2A, base2[q + 4]);
            tA1 = __builtin_elementwise_fma(ee2[q + 4], d2A, tA1);
            a1A.h[q] = __builtin_elementwise_max(tA1, zero2);
            half2v tB0 = __builtin_elementwise_fma(cc2[q], wj2B, base2[q]);
            tB0 = __builtin_elementwise_fma(ee2[q], d2B, tB0);
            a0B.h[q] = __builtin_elementwise_max(tB0, zero2);
            half2v tB1 = __builtin_elementwise_fma(cc2[q + 4], wj2B, base2[q + 4]);
            tB1 = __builtin_elementwise_fma(ee2[q + 4], d2B, tB1);
            a1B.h[q] = __builtin_elementwise_max(tB1, zero2);
        }

        // ---- Layer 2: two independent MFMA chains ----
        floatx16 accA = __builtin_amdgcn_mfma_f32_32x32x16_f16(a0, a0A.v, cinit, 0, 0, 0);
        floatx16 accB = __builtin_amdgcn_mfma_f32_32x32x16_f16(a0, a0B.v, cinit, 0, 0, 0);
        accA = __builtin_amdgcn_mfma_f32_32x32x16_f16(a1, a1A.v, accA, 0, 0, 0);
        accB = __builtin_amdgcn_mfma_f32_32x32x16_f16(a1, a1B.v, accB, 0, 0, 0);

        // ---- Layer 3: relu + W3 dot, two tiles interleaved ----
        float sA0 = 0.0f, sA1 = 0.0f, sB0 = 0.0f, sB1 = 0.0f;
#pragma unroll
        for (int r = 0; r < 16; r += 2) {
            sA0 = fmaf(fmaxf(accA[r + 0], 0.0f), w3r[r + 0], sA0);
            sA1 = fmaf(fmaxf(accA[r + 1], 0.0f), w3r[r + 1], sA1);
            sB0 = fmaf(fmaxf(accB[r + 0], 0.0f), w3r[r + 0], sB0);
            sB1 = fmaf(fmaxf(accB[r + 1], 0.0f), w3r[r + 1], sB1);
        }
        const float sA = sA0 + sA1;
        const float sB = sB0 + sB1;

        // One shuffle resolves both tiles: send the tile the other half needs.
        const float u = hi ? sA : sB;
        const float other = __shfl_xor(u, 32, 64);
        const float loc = hi ? sB : sA;
        const float full = loc + other;  // lane<32: tileA col; lane>=32: tileB col

        // softplus(x) = max(x,0) + log(1 + exp(-|x|)), 64 distinct pixels
        const float x = full + b3v;
        const float sp = fmaxf(x, 0.0f) + __logf(1.0f + __expf(-fabsf(x)));

        orow[j0 + lane] = sp;  // coalesced 256B, all 64 lanes

        dA = dA_n; wjA = wjA_n; dB = dB_n; wjB = wjB_n;
    }
}

extern "C" void kernel_launch(void* const* d_in, const int* in_sizes, int n_in,
                              void* d_out, int out_size, void* d_ws, size_t ws_size,
                              hipStream_t stream) {
    const float* weights   = (const float*)d_in[0];
    const float* distances = (const float*)d_in[1];
    const float* W1 = (const float*)d_in[2];
    const float* b1 = (const float*)d_in[3];
    const float* W2 = (const float*)d_in[4];
    const float* b2 = (const float*)d_in[5];
    const float* W3 = (const float*)d_in[6];
    const float* b3 = (const float*)d_in[7];
    float* out = (float*)d_out;

    const int rows_total = 4 * 1024;            // B * N
    dim3 grid(rows_total * (NDIM / SEG) / 4);   // 4 waves/block, half-row each
    lf_kernel<<<grid, 256, 0, stream>>>(weights, distances, W1, b1, W2, b2, W3, b3, out);
}